// Round 1
// baseline (376.064 us; speedup 1.0000x reference)
//
#include <hip/hip_runtime.h>
#include <hip/hip_bf16.h>
#include <math.h>

// Problem constants
#define H_ 16
#define KC_ 16
#define ZD_ 64
#define OC_ 128
#define IC_ 128
#define KW_ 3
#define HID_ 256
#define O_ 2048
#define I_ 2048
#define NPDE_ 1024
#define DPDE_ 64
#define NW2_ 49152            // OC*IC*KW
#define W2D_OUT (O_ * I_ * KW_ * 3)   // 37748736

// ---------------------------------------------------------------------------
// Kernel A: feat[256] = b1 + mean(pde_inputs,axis=0) @ U1       (1 block)
// ---------------------------------------------------------------------------
__global__ void feat_kernel(const float* __restrict__ pde,
                            const float* __restrict__ U1,
                            const float* __restrict__ b1,
                            float* __restrict__ feat_ws) {
    __shared__ float partial[256];
    __shared__ float meanv[64];
    const int t = threadIdx.x;
    const int col = t & 63;
    const int seg = t >> 6;            // 4 row-segments of 256 rows
    float s = 0.f;
    const int r0 = seg * 256;
    for (int r = 0; r < 256; ++r) s += pde[(r0 + r) * DPDE_ + col];
    partial[t] = s;
    __syncthreads();
    if (t < 64) {
        meanv[t] = (partial[t] + partial[t + 64] + partial[t + 128] + partial[t + 192]) * (1.f / 1024.f);
    }
    __syncthreads();
    float f = b1[t];
    #pragma unroll
    for (int d = 0; d < 64; ++d) f = fmaf(meanv[d], U1[d * HID_ + t], f);
    feat_ws[t] = f;
}

// ---------------------------------------------------------------------------
// Kernel B: hiddenT[j][m] = tanh(Z[m,:]@W1[:,j] + feat[j])  (stored TRANSPOSED)
// grid 256 (m), block 256 (j)
// ---------------------------------------------------------------------------
__global__ void hidden_kernel(const float* __restrict__ Z,
                              const float* __restrict__ W1,
                              const float* __restrict__ feat_ws,
                              float* __restrict__ hiddenT) {
    __shared__ float zr[64];
    const int m = blockIdx.x;
    const int j = threadIdx.x;
    if (j < 64) zr[j] = Z[m * ZD_ + j];
    __syncthreads();
    float s = feat_ws[j];
    #pragma unroll
    for (int d = 0; d < 64; ++d) s = fmaf(zr[d], W1[d * HID_ + j], s);
    hiddenT[j * 256 + m] = tanhf(s);   // transposed: [k][m]
}

// ---------------------------------------------------------------------------
// Kernel C: bb[o] = z_bias[o] + unet_1d_bias[o]
// ---------------------------------------------------------------------------
__global__ void bias_kernel(const float* __restrict__ z_bias,
                            const float* __restrict__ u_bias,
                            float* __restrict__ out_bb) {
    const int idx = blockIdx.x * 256 + threadIdx.x;
    if (idx < O_) out_bb[idx] = z_bias[idx] + u_bias[idx];
}

// ---------------------------------------------------------------------------
// Kernel D: fused GEMM (hiddenT^T @ W2 + b2) + outer product with unet -> w_2d
// grid 512 = (oc in [0,128)) x (icq in [0,4)), block 256 threads.
// Thread t owns 4 m-rows (mt=4*(t&63)) x 24 n-cols (jt=24*(t>>6)).
// ---------------------------------------------------------------------------
__global__ __launch_bounds__(256, 2)
void fused_main(const float* __restrict__ hiddenT,
                const float* __restrict__ W2,
                const float* __restrict__ b2,
                const float* __restrict__ unet,
                float* __restrict__ out) {
    __shared__ float h_t[32 * 256];    // [kk_local][m]   32 KB
    __shared__ float w2c[32 * 96];     // [kk_local][j]   12 KB

    const int t = threadIdx.x;
    const int oc = blockIdx.x & 127;
    const int icq = blockIdx.x >> 7;           // 0..3
    const int n0 = oc * 384 + icq * 96;        // first W2 column of this block
    const int mt = (t & 63) * 4;               // 4 consecutive m rows
    const int wgrp = t >> 6;                   // wave id, uniform per wave
    const int jt = wgrp * 24;                  // 24 consecutive j cols

    float acc[4][24];
    #pragma unroll
    for (int a = 0; a < 4; ++a)
        #pragma unroll
        for (int b = 0; b < 24; ++b) acc[a][b] = 0.f;

    for (int c8 = 0; c8 < 8; ++c8) {           // K chunks of 32
        // stage hidden chunk: contiguous 8192 floats (hiddenT is [k][m])
        const float4* hsrc = (const float4*)(hiddenT + c8 * 32 * 256);
        float4* hdst = (float4*)h_t;
        #pragma unroll
        for (int q = 0; q < 8; ++q) hdst[q * 256 + t] = hsrc[q * 256 + t];
        // stage W2 chunk: 32 rows x 96 cols (row stride 49152)
        float4* wdst = (float4*)w2c;
        #pragma unroll
        for (int q = 0; q < 3; ++q) {
            const int e = q * 256 + t;         // 0..767 float4s
            const int kk = e / 24;
            const int j4 = e - kk * 24;
            wdst[e] = *(const float4*)(W2 + (size_t)(c8 * 32 + kk) * NW2_ + n0 + j4 * 4);
        }
        __syncthreads();

        #pragma unroll
        for (int kk = 0; kk < 32; ++kk) {
            const float4 hf = *(const float4*)&h_t[kk * 256 + mt];
            float wv[24];
            #pragma unroll
            for (int u = 0; u < 6; ++u)
                *(float4*)&wv[u * 4] = *(const float4*)&w2c[kk * 96 + jt + u * 4];
            const float hs[4] = {hf.x, hf.y, hf.z, hf.w};
            #pragma unroll
            for (int a = 0; a < 4; ++a)
                #pragma unroll
                for (int b = 0; b < 24; ++b)
                    acc[a][b] = fmaf(hs[a], wv[b], acc[a][b]);
        }
        __syncthreads();
    }

    // bias for this thread's 24 columns
    float b2v[24];
    #pragma unroll
    for (int u = 0; u < 6; ++u)
        *(float4*)&b2v[u * 4] = *(const float4*)(b2 + n0 + jt + u * 4);

    // writeout: for each owned m, a contiguous, 16B-aligned 72-float run
    #pragma unroll
    for (int a = 0; a < 4; ++a) {
        const int m = mt + a;
        const int h = m >> 4;
        const int kc = m & 15;
        const int o = h * 128 + oc;
        const int i00 = kc * 128 + icq * 32 + wgrp * 8;   // multiple of 8
        const size_t base = (size_t)o * 2048 + i00;
        const float* ub = unet + base * 3;
        float* ob = out + base * 9;
        float u[24];
        #pragma unroll
        for (int q = 0; q < 6; ++q) *(float4*)&u[q * 4] = *(const float4*)(ub + q * 4);
        #pragma unroll
        for (int q = 0; q < 18; ++q) {
            float tmp[4];
            #pragma unroll
            for (int r = 0; r < 4; ++r) {
                const int idx = q * 4 + r;     // = dj*3 + l
                const int dj = idx / 3;
                const int l = idx - dj * 3;
                tmp[r] = (acc[a][dj] + b2v[dj]) * u[(dj / 3) * 3 + l];
            }
            float4 v; v.x = tmp[0]; v.y = tmp[1]; v.z = tmp[2]; v.w = tmp[3];
            *(float4*)(ob + q * 4) = v;
        }
    }
}

// ---------------------------------------------------------------------------
extern "C" void kernel_launch(void* const* d_in, const int* in_sizes, int n_in,
                              void* d_out, int out_size, void* d_ws, size_t ws_size,
                              hipStream_t stream) {
    const float* Z       = (const float*)d_in[0];
    const float* z_bias  = (const float*)d_in[1];
    const float* unet_w  = (const float*)d_in[2];
    const float* unet_b  = (const float*)d_in[3];
    const float* pde     = (const float*)d_in[4];
    const float* W1      = (const float*)d_in[5];
    const float* U1      = (const float*)d_in[6];
    const float* b1      = (const float*)d_in[7];
    const float* W2      = (const float*)d_in[8];
    const float* b2      = (const float*)d_in[9];
    float* out = (float*)d_out;

    float* feat_ws = (float*)d_ws;            // 256 floats
    float* hiddenT = feat_ws + 256;           // 65536 floats, [k][m] transposed

    feat_kernel<<<1, 256, 0, stream>>>(pde, U1, b1, feat_ws);
    hidden_kernel<<<256, 256, 0, stream>>>(Z, W1, feat_ws, hiddenT);
    bias_kernel<<<8, 256, 0, stream>>>(z_bias, unet_b, out + W2D_OUT);
    fused_main<<<512, 256, 0, stream>>>(hiddenT, W2, b2, unet_w, out);
}

// Round 2
// 330.454 us; speedup vs baseline: 1.1380x; 1.1380x over previous
//
#include <hip/hip_runtime.h>
#include <hip/hip_bf16.h>
#include <math.h>

#define H_ 16
#define KC_ 16
#define ZD_ 64
#define OC_ 128
#define IC_ 128
#define KW_ 3
#define HID_ 256
#define O_ 2048
#define I_ 2048
#define NW2_ 49152                    // OC*IC*KW columns of W2
#define W2D_OUT (O_ * I_ * KW_ * 3)  // 37748736

typedef short bf16x8 __attribute__((ext_vector_type(8)));
typedef float f32x4 __attribute__((ext_vector_type(4)));

static __device__ __forceinline__ unsigned short f2bf(float f) {
    union { float f; unsigned u; } v; v.f = f;
    unsigned r = v.u + 0x7FFF + ((v.u >> 16) & 1);   // RNE
    return (unsigned short)(r >> 16);
}

// ---------------------------------------------------------------------------
// Prep: per-block redundant mean+feat (pde L2-cached), hidden row in bf16,
// bb for blocks 0..7.  grid 256 x 256.
// ---------------------------------------------------------------------------
__global__ void prep_kernel(const float* __restrict__ Z,
                            const float* __restrict__ pde,
                            const float* __restrict__ W1,
                            const float* __restrict__ U1,
                            const float* __restrict__ b1,
                            const float* __restrict__ z_bias,
                            const float* __restrict__ u_bias,
                            unsigned short* __restrict__ hidden_bf,
                            float* __restrict__ out_bb) {
    __shared__ float part[16][64];
    __shared__ float meanv[64];
    __shared__ float zr[64];
    const int t = threadIdx.x, m = blockIdx.x;
    if (t < 64) zr[t] = Z[m * ZD_ + t];
    const int c4 = t & 15, rg = t >> 4;
    float sx = 0.f, sy = 0.f, sz = 0.f, sw = 0.f;
    const float4* p = (const float4*)pde;      // 16 float4 per 64-col row
    for (int r = 0; r < 64; ++r) {
        float4 v = p[(rg * 64 + r) * 16 + c4];
        sx += v.x; sy += v.y; sz += v.z; sw += v.w;
    }
    part[rg][c4 * 4 + 0] = sx; part[rg][c4 * 4 + 1] = sy;
    part[rg][c4 * 4 + 2] = sz; part[rg][c4 * 4 + 3] = sw;
    __syncthreads();
    if (t < 64) {
        float a = 0.f;
        #pragma unroll
        for (int g = 0; g < 16; ++g) a += part[g][t];
        meanv[t] = a * (1.f / 1024.f);
    }
    __syncthreads();
    float f = b1[t];
    #pragma unroll
    for (int d = 0; d < 64; ++d) f = fmaf(meanv[d], U1[d * HID_ + t], f);
    float s = f;
    #pragma unroll
    for (int d = 0; d < 64; ++d) s = fmaf(zr[d], W1[d * HID_ + t], s);
    hidden_bf[m * HID_ + t] = f2bf(tanhf(s));
    if (m < 8) {
        const int idx = m * 256 + t;
        out_bb[idx] = z_bias[idx] + u_bias[idx];
    }
}

// ---------------------------------------------------------------------------
// Fused MFMA GEMM + expansion.
// grid 1024: block b -> oc = b>>3 (0..127), hp = b&7 (0..7).
// Block computes w rows m = (hp*2+{0,1})*16 + kc for all kc, cols oc*384..+383,
// then writes out[o= h*128+oc][i][k][l] = (w + b2) * unet — contiguous runs.
// Each wave: h = hp*2 + (wave&1), n-half = (wave>>1)*192 (12 n-tiles of 16).
// ---------------------------------------------------------------------------
__global__ __launch_bounds__(256, 4)
void gemm_expand(const unsigned short* __restrict__ hidden_bf,
                 const float* __restrict__ W2,
                 const float* __restrict__ b2,
                 const float* __restrict__ unet,
                 float* __restrict__ out) {
    // B chunk transposed: bT[n(384)][k(32)] bf16, row padded to 40 ushorts (80B)
    __shared__ unsigned short bT[384 * 40];

    const int t = threadIdx.x;
    const int lane = t & 63;
    const int wave = t >> 6;
    const int oc = blockIdx.x >> 3;
    const int hp = blockIdx.x & 7;
    const int h = hp * 2 + (wave & 1);
    const int wn0 = (wave >> 1) * 192;
    const int n15 = lane & 15;
    const int quad = lane >> 4;
    const int n0g = oc * 384;
    const int kg = wave;                 // staging: wave stages its 8 k-rows

    f32x4 acc[12];
    #pragma unroll
    for (int i = 0; i < 12; ++i) acc[i] = (f32x4){0.f, 0.f, 0.f, 0.f};

    const unsigned short* arow = hidden_bf + (h * 16 + n15) * HID_;

    for (int c = 0; c < 8; ++c) {
        // ---- stage W2 chunk [32k x 384n] fp32 -> bT bf16 transposed ----
        #pragma unroll
        for (int it = 0; it < 6; ++it) {
            const int n = it * 64 + lane;
            const float* src = W2 + (size_t)(c * 32 + kg * 8) * NW2_ + n0g + n;
            unsigned short u8[8];
            #pragma unroll
            for (int jj = 0; jj < 8; ++jj)
                u8[jj] = f2bf(src[(size_t)jj * NW2_]);
            *(bf16x8*)&bT[n * 40 + kg * 8] = *(bf16x8*)u8;
        }
        __syncthreads();
        // ---- MFMA ----
        const bf16x8 a = *(const bf16x8*)(arow + c * 32 + quad * 8);
        #pragma unroll
        for (int nt = 0; nt < 12; ++nt) {
            const bf16x8 bfr = *(const bf16x8*)&bT[(wn0 + nt * 16 + n15) * 40 + quad * 8];
            acc[nt] = __builtin_amdgcn_mfma_f32_16x16x32_bf16(a, bfr, acc[nt], 0, 0, 0);
        }
        __syncthreads();
    }

    // ---- epilogue: out[o][i][k][l] = (w + b2[n]) * unet[o][i][l] ----
    const int o = h * 128 + oc;
    const size_t obase = (size_t)o * 18432;
    const size_t ubase = (size_t)o * 6144;
    #pragma unroll
    for (int nt = 0; nt < 12; ++nt) {
        const int n_rel = wn0 + nt * 16 + n15;          // 0..383 = ic*3 + k
        const int ic = (n_rel * 171) >> 9;              // /3 for n<512
        const float gb2 = b2[n0g + n_rel];
        #pragma unroll
        for (int r = 0; r < 4; ++r) {
            const int kc = quad * 4 + r;
            const float w = acc[nt][r] + gb2;
            const float* ub = unet + ubase + kc * 384 + ic * 3;
            float* ob = out + obase + kc * 1152 + n_rel * 3;
            ob[0] = w * ub[0];
            ob[1] = w * ub[1];
            ob[2] = w * ub[2];
        }
    }
}

// ---------------------------------------------------------------------------
extern "C" void kernel_launch(void* const* d_in, const int* in_sizes, int n_in,
                              void* d_out, int out_size, void* d_ws, size_t ws_size,
                              hipStream_t stream) {
    const float* Z       = (const float*)d_in[0];
    const float* z_bias  = (const float*)d_in[1];
    const float* unet_w  = (const float*)d_in[2];
    const float* unet_b  = (const float*)d_in[3];
    const float* pde     = (const float*)d_in[4];
    const float* W1      = (const float*)d_in[5];
    const float* U1      = (const float*)d_in[6];
    const float* b1      = (const float*)d_in[7];
    const float* W2      = (const float*)d_in[8];
    const float* b2      = (const float*)d_in[9];
    float* out = (float*)d_out;

    unsigned short* hidden_bf = (unsigned short*)d_ws;   // 256*256 bf16 = 128 KB

    prep_kernel<<<256, 256, 0, stream>>>(Z, pde, W1, U1, b1, z_bias, unet_b,
                                         hidden_bf, out + W2D_OUT);
    gemm_expand<<<1024, 256, 0, stream>>>(hidden_bf, W2, b2, unet_w, out);
}

// Round 4
// 278.862 us; speedup vs baseline: 1.3486x; 1.1850x over previous
//
#include <hip/hip_runtime.h>
#include <hip/hip_bf16.h>
#include <math.h>

#define H_ 16
#define KC_ 16
#define ZD_ 64
#define HID_ 256
#define O_ 2048
#define NW2_ 49152                    // OC*IC*KW columns of W2
#define W2D_OUT 37748736              // O*I*KW*L
#define DPDE_ 64

typedef short bf16x8 __attribute__((ext_vector_type(8)));
typedef float f32x4 __attribute__((ext_vector_type(4)));

struct F3 { float x, y, z; };         // 12B, 4B-aligned -> dwordx3

static __device__ __forceinline__ unsigned short f2bf(float f) {
    union { float f; unsigned u; } v; v.f = f;
    unsigned r = v.u + 0x7FFF + ((v.u >> 16) & 1);   // RNE
    return (unsigned short)(r >> 16);
}

// ---------------------------------------------------------------------------
// Prep: per-block redundant mean+feat (pde L2-cached), hidden in MFMA-A layout
// hiddenA[k>>3][m][k&7] bf16, plus bb for blocks 0..7.  grid 256 x 256.
// ---------------------------------------------------------------------------
__global__ void prep_kernel(const float* __restrict__ Z,
                            const float* __restrict__ pde,
                            const float* __restrict__ W1,
                            const float* __restrict__ U1,
                            const float* __restrict__ b1,
                            const float* __restrict__ z_bias,
                            const float* __restrict__ u_bias,
                            unsigned short* __restrict__ hiddenA,
                            float* __restrict__ out_bb) {
    __shared__ float part[16][64];
    __shared__ float meanv[64];
    __shared__ float zr[64];
    const int t = threadIdx.x, m = blockIdx.x;
    if (t < 64) zr[t] = Z[m * ZD_ + t];
    const int c4 = t & 15, rg = t >> 4;
    float sx = 0.f, sy = 0.f, sz = 0.f, sw = 0.f;
    const float4* p = (const float4*)pde;      // 16 float4 per 64-col row
    for (int r = 0; r < 64; ++r) {
        float4 v = p[(rg * 64 + r) * 16 + c4];
        sx += v.x; sy += v.y; sz += v.z; sw += v.w;
    }
    part[rg][c4 * 4 + 0] = sx; part[rg][c4 * 4 + 1] = sy;
    part[rg][c4 * 4 + 2] = sz; part[rg][c4 * 4 + 3] = sw;
    __syncthreads();
    if (t < 64) {
        float a = 0.f;
        #pragma unroll
        for (int g = 0; g < 16; ++g) a += part[g][t];
        meanv[t] = a * (1.f / 1024.f);
    }
    __syncthreads();
    float f = b1[t];
    #pragma unroll
    for (int d = 0; d < 64; ++d) f = fmaf(meanv[d], U1[d * HID_ + t], f);
    float s = f;
    #pragma unroll
    for (int d = 0; d < 64; ++d) s = fmaf(zr[d], W1[d * HID_ + t], s);
    // MFMA-A-native layout: hiddenA[(k/8)*256 + m][k%8]
    hiddenA[((size_t)(t >> 3) * 256 + m) * 8 + (t & 7)] = f2bf(tanhf(s));
    if (m < 8) {
        const int idx = m * 256 + t;
        out_bb[idx] = z_bias[idx] + u_bias[idx];
    }
}

// ---------------------------------------------------------------------------
// Fused MFMA GEMM + expansion, single-fetch W2.
// grid 512: block -> oc = b>>2 (0..127), icq = b&3.  512 threads = 8 waves.
// Block: all m (256 rows) x 96 n-cols (n0g = oc*384 + icq*96), k = 256.
// Wave w owns m-tiles 2w, 2w+1 (rows 32w..32w+31); 6 n-tiles of 16.
// K staged in 4 chunks of 64.
// ---------------------------------------------------------------------------
__global__ __launch_bounds__(512, 4)
void gemm_expand(const unsigned short* __restrict__ hiddenA,
                 const float* __restrict__ W2,
                 const float* __restrict__ b2,
                 const float* __restrict__ unet,
                 float* __restrict__ out) {
    // B chunk transposed: bT[n(96)][k(64)] bf16, row padded to 72 (144B, 16B-aligned)
    __shared__ unsigned short bT[96 * 72];

    const int t = threadIdx.x;
    const int lane = t & 63;
    const int wave = t >> 6;                  // 0..7
    const int n15 = lane & 15;
    const int quad = lane >> 4;
    const int oc = blockIdx.x >> 2;
    const int icq = blockIdx.x & 3;
    const int n0g = oc * 384 + icq * 96;

    f32x4 acc[2][6];
    #pragma unroll
    for (int a = 0; a < 2; ++a)
        #pragma unroll
        for (int b = 0; b < 6; ++b) acc[a][b] = (f32x4){0.f, 0.f, 0.f, 0.f};

    for (int c = 0; c < 4; ++c) {
        // ---- stage W2 chunk [64k x 96n] fp32 -> bT bf16 transposed ----
        #pragma unroll
        for (int i = 0; i < 3; ++i) {
            const int e = i * 512 + t;        // 0..1535 float4 units
            const int kk = e / 24;            // 0..63
            const int nq = e - kk * 24;       // 0..23 (n = nq*4)
            const float4 v = *(const float4*)(W2 + (size_t)(c * 64 + kk) * NW2_ + n0g + nq * 4);
            unsigned short* d = &bT[(nq * 4) * 72 + kk];
            d[0]       = f2bf(v.x);
            d[72]      = f2bf(v.y);
            d[144]     = f2bf(v.z);
            d[216]     = f2bf(v.w);
        }
        __syncthreads();
        // ---- MFMA: 2 k-steps of 32 ----
        #pragma unroll
        for (int kh = 0; kh < 2; ++kh) {
            const int g = c * 8 + kh * 4 + quad;
            bf16x8 afr[2];
            #pragma unroll
            for (int mi = 0; mi < 2; ++mi)
                afr[mi] = *(const bf16x8*)(hiddenA +
                          ((size_t)g * 256 + (wave * 2 + mi) * 16 + n15) * 8);
            #pragma unroll
            for (int nt = 0; nt < 6; ++nt) {
                const bf16x8 bfr = *(const bf16x8*)&bT[(nt * 16 + n15) * 72 + kh * 32 + quad * 8];
                acc[0][nt] = __builtin_amdgcn_mfma_f32_16x16x32_bf16(afr[0], bfr, acc[0][nt], 0, 0, 0);
                acc[1][nt] = __builtin_amdgcn_mfma_f32_16x16x32_bf16(afr[1], bfr, acc[1][nt], 0, 0, 0);
            }
        }
        __syncthreads();
    }

    // ---- epilogue: out[o][i][kw][l] = (w + b2) * unet[o][i][l], dwordx3 I/O ----
    #pragma unroll
    for (int mi = 0; mi < 2; ++mi) {
        const int o = (wave * 2 + mi) * 128 + oc;
        const float* ub_o = unet + (size_t)o * 6144;
        float* ob_o = out + (size_t)o * 18432;
        #pragma unroll
        for (int nt = 0; nt < 6; ++nt) {
            const int nl = nt * 16 + n15;         // 0..95 (col within block strip)
            const int n_rel = icq * 96 + nl;      // 0..383 = ic*3 + kw
            const int ic = n_rel / 3;
            const float gb2 = b2[n0g + nl];       // FIXED: global col = n0g + nl
            #pragma unroll
            for (int r = 0; r < 4; ++r) {
                const int kc = quad * 4 + r;
                const float w = acc[mi][nt][r] + gb2;
                const F3 u = *(const F3*)(ub_o + kc * 384 + ic * 3);
                F3 res; res.x = w * u.x; res.y = w * u.y; res.z = w * u.z;
                *(F3*)(ob_o + kc * 1152 + n_rel * 3) = res;
            }
        }
    }
}

// ---------------------------------------------------------------------------
extern "C" void kernel_launch(void* const* d_in, const int* in_sizes, int n_in,
                              void* d_out, int out_size, void* d_ws, size_t ws_size,
                              hipStream_t stream) {
    const float* Z       = (const float*)d_in[0];
    const float* z_bias  = (const float*)d_in[1];
    const float* unet_w  = (const float*)d_in[2];
    const float* unet_b  = (const float*)d_in[3];
    const float* pde     = (const float*)d_in[4];
    const float* W1      = (const float*)d_in[5];
    const float* U1      = (const float*)d_in[6];
    const float* b1      = (const float*)d_in[7];
    const float* W2      = (const float*)d_in[8];
    const float* b2      = (const float*)d_in[9];
    float* out = (float*)d_out;

    unsigned short* hiddenA = (unsigned short*)d_ws;   // 256*256 bf16 = 128 KB

    prep_kernel<<<256, 256, 0, stream>>>(Z, pde, W1, U1, b1, z_bias, unet_b,
                                         hiddenA, out + W2D_OUT);
    gemm_expand<<<512, 512, 0, stream>>>(hiddenA, W2, b2, unet_w, out);
}